// Round 1
// baseline (435.388 us; speedup 1.0000x reference)
//
#include <hip/hip_runtime.h>
#include <math.h>

#define TOKW 32   // window size
#define DIMS 256  // feature dim

// One block per 32-token window. 256 threads = 8 threads/token x 32 dims/thread.
__global__ __launch_bounds__(256) void focus_kernel(
    const float* __restrict__ x,
    float* __restrict__ out_mask,
    float* __restrict__ out_comp)
{
    const int w   = blockIdx.x;
    const int tid = threadIdx.x;
    const int tok = tid >> 3;   // 0..31 token within window
    const int lt  = tid & 7;    // 0..7 sub-lane within token

    __shared__ float sh_xn[TOKW][DIMS];  // normalized tile, 32 KB
    __shared__ float sh_prev[DIMS];      // normalized prev-window boundary token
    __shared__ float sh_s[DIMS];         // window sum of normalized tokens
    __shared__ float sh_m[TOKW];         // mean_sim per token

    const long long g0 = (long long)w * TOKW;          // first global token of window
    const long long tokbase = (g0 + tok) * (DIMS / 4); // float4 index of this token's row
    const float4* xv = (const float4*)x;

    // ---- load tile: 8 float4 per thread (token row, interleaved by lt)
    float4 v[8];
#pragma unroll
    for (int j = 0; j < 8; ++j)
        v[j] = xv[tokbase + lt + 8 * j];

    // ---- per-token L2 norm (reduce over the 8 lanes of this token)
    float ss = 0.f;
#pragma unroll
    for (int j = 0; j < 8; ++j)
        ss += v[j].x * v[j].x + v[j].y * v[j].y + v[j].z * v[j].z + v[j].w * v[j].w;
    ss += __shfl_xor(ss, 1);
    ss += __shfl_xor(ss, 2);
    ss += __shfl_xor(ss, 4);
    const float rn = 1.0f / fmaxf(sqrtf(ss), 1e-12f);

    // ---- store normalized tile to LDS
#pragma unroll
    for (int j = 0; j < 8; ++j) {
        float4 n4 = make_float4(v[j].x * rn, v[j].y * rn, v[j].z * rn, v[j].w * rn);
        *(float4*)&sh_xn[tok][4 * (lt + 8 * j)] = n4;
    }

    // ---- wave 0: load + normalize the previous window's last token (global token g0-1)
    if (tid < 64) {
        float4 pv = make_float4(0.f, 0.f, 0.f, 0.f);
        if (w > 0) pv = xv[(g0 - 1) * (DIMS / 4) + tid];
        float ps = pv.x * pv.x + pv.y * pv.y + pv.z * pv.z + pv.w * pv.w;
        ps += __shfl_xor(ps, 1);
        ps += __shfl_xor(ps, 2);
        ps += __shfl_xor(ps, 4);
        ps += __shfl_xor(ps, 8);
        ps += __shfl_xor(ps, 16);
        ps += __shfl_xor(ps, 32);
        const float prn = 1.0f / fmaxf(sqrtf(ps), 1e-12f);
        // w==0: pv is zero -> stores zeros -> sim_adj=0<0.7 -> mask3[0]=true (matches ref)
        *(float4*)&sh_prev[tid * 4] =
            make_float4(pv.x * prn, pv.y * prn, pv.z * prn, pv.w * prn);
    }

    __syncthreads();

    // ---- window sum s[d] = sum_t xn[t][d]  (thread d handles one dim)
    {
        float acc = 0.f;
#pragma unroll
        for (int t = 0; t < TOKW; ++t)
            acc += sh_xn[t][tid];
        sh_s[tid] = acc;
    }
    __syncthreads();

    // ---- mean_sim[tok] = dot(xn_tok, s) / 32 = rn * dot(x_tok, s) / 32
    {
        float dp = 0.f;
#pragma unroll
        for (int j = 0; j < 8; ++j) {
            float4 s4 = *(const float4*)&sh_s[4 * (lt + 8 * j)];
            dp += v[j].x * s4.x + v[j].y * s4.y + v[j].z * s4.z + v[j].w * s4.w;
        }
        dp += __shfl_xor(dp, 1);
        dp += __shfl_xor(dp, 2);
        dp += __shfl_xor(dp, 4);
        if (lt == 0) sh_m[tok] = dp * rn * (1.0f / 32.0f);
    }
    __syncthreads();

    // ---- window stats (computed redundantly by every thread; 32-way LDS broadcasts)
    float mu = 0.f;
#pragma unroll
    for (int t = 0; t < TOKW; ++t)
        mu += sh_m[t];
    mu *= (1.0f / 32.0f);

    float var = 0.f;
#pragma unroll
    for (int t = 0; t < TOKW; ++t) {
        float d = sh_m[t] - mu;
        var += d * d;
    }
    var *= (1.0f / 31.0f);  // ddof=1 (unbiased, matches torch/jnp std)
    const float thr = mu + sqrtf(var);

    int cnt = 0, amin = 0;
    float mmin = sh_m[0];
#pragma unroll
    for (int t = 0; t < TOKW; ++t) {
        float m = sh_m[t];
        cnt += (m <= thr) ? 1 : 0;
        if (m < mmin) { mmin = m; amin = t; }  // first-min, matches argmin
    }

    // ---- write mask1 (stage-1 keep mask) as 0.0/1.0
    if (tid < TOKW) {
        bool k = (cnt > 0) ? (sh_m[tid] <= thr) : (tid == amin);
        out_mask[g0 + tid] = k ? 1.0f : 0.0f;
    }

    // ---- stage 3: adjacent cosine sim: dot(xn[tok-1], xn[tok])
    const float* prevrow = (tok == 0) ? sh_prev : sh_xn[tok - 1];
    float ap = 0.f;
#pragma unroll
    for (int j = 0; j < 8; ++j) {
        float4 p4 = *(const float4*)&prevrow[4 * (lt + 8 * j)];
        ap += v[j].x * p4.x + v[j].y * p4.y + v[j].z * p4.z + v[j].w * p4.w;
    }
    ap += __shfl_xor(ap, 1);
    ap += __shfl_xor(ap, 2);
    ap += __shfl_xor(ap, 4);
    const float sim_adj = ap * rn;
    const float mult = (sim_adj < 0.7f) ? 1.0f : 0.0f;

    // ---- write compressed = x * mask3
    float4* ov = (float4*)out_comp;
#pragma unroll
    for (int j = 0; j < 8; ++j)
        ov[tokbase + lt + 8 * j] =
            make_float4(v[j].x * mult, v[j].y * mult, v[j].z * mult, v[j].w * mult);
}

extern "C" void kernel_launch(void* const* d_in, const int* in_sizes, int n_in,
                              void* d_out, int out_size, void* d_ws, size_t ws_size,
                              hipStream_t stream) {
    const float* x = (const float*)d_in[0];
    const int ND = in_sizes[0];     // N * D
    const int N  = ND / DIMS;       // 262144
    const int nw = N / TOKW;        // 8192 windows

    float* out_mask = (float*)d_out;       // first N floats: mask1 (0/1)
    float* out_comp = out_mask + N;        // then N*D floats: compressed

    focus_kernel<<<nw, 256, 0, stream>>>(x, out_mask, out_comp);
}